// Round 1
// baseline (1807.751 us; speedup 1.0000x reference)
//
#include <hip/hip_runtime.h>
#include <math.h>

#define EPS 1e-5f

constexpr int B = 8, S = 1024, E = 512, H = 8, DH = 64;
constexpr int M = B * S;          // 8192 rows
constexpr int TQ = 8;             // q rows per attention block

// ---------------------------------------------------------------------------
// LN stats: per-row mean and rsqrt(var+eps). One block (256 thr) per row of E=512.
// ---------------------------------------------------------------------------
__global__ __launch_bounds__(256) void ln_stats_kernel(
    const float* __restrict__ x, float* __restrict__ mu, float* __restrict__ rs) {
    int row = blockIdx.x;
    const float* xr = x + (size_t)row * E;
    int t = threadIdx.x;
    float a = xr[t], c = xr[t + 256];
    __shared__ float red[256];
    red[t] = a + c; __syncthreads();
    for (int s2 = 128; s2 > 0; s2 >>= 1) { if (t < s2) red[t] += red[t + s2]; __syncthreads(); }
    float m = red[0] * (1.0f / E);
    __syncthreads();
    float d0 = a - m, d1 = c - m;
    red[t] = d0 * d0 + d1 * d1; __syncthreads();
    for (int s2 = 128; s2 > 0; s2 >>= 1) { if (t < s2) red[t] += red[t + s2]; __syncthreads(); }
    if (t == 0) { mu[row] = m; rs[row] = rsqrtf(red[0] * (1.0f / E) + EPS); }
}

// ---------------------------------------------------------------------------
// Full LN: out = (x - mu) * rsqrt(var+eps) * w + b   (final output stage)
// ---------------------------------------------------------------------------
__global__ __launch_bounds__(256) void ln_full_kernel(
    const float* __restrict__ x, const float* __restrict__ w,
    const float* __restrict__ bb, float* __restrict__ out) {
    int row = blockIdx.x;
    const float* xr = x + (size_t)row * E;
    int t = threadIdx.x;
    float a = xr[t], c = xr[t + 256];
    __shared__ float red[256];
    red[t] = a + c; __syncthreads();
    for (int s2 = 128; s2 > 0; s2 >>= 1) { if (t < s2) red[t] += red[t + s2]; __syncthreads(); }
    float m = red[0] * (1.0f / E);
    __syncthreads();
    float d0 = a - m, d1 = c - m;
    red[t] = d0 * d0 + d1 * d1; __syncthreads();
    for (int s2 = 128; s2 > 0; s2 >>= 1) { if (t < s2) red[t] += red[t + s2]; __syncthreads(); }
    float r = rsqrtf(red[0] * (1.0f / E) + EPS);
    float* orow = out + (size_t)row * E;
    orow[t]       = d0 * r * w[t]       + bb[t];
    orow[t + 256] = d1 * r * w[t + 256] + bb[t + 256];
}

// ---------------------------------------------------------------------------
// Tiled fp32 GEMM: C[M,N] = op(A)[M,K] @ W[N,K]^T + bias (+ epilogue)
//   LN_A: normalize A rows on the fly with (mu,rs) and scale by lnw/lnb (fused LayerNorm)
//   RES_MODE 0: none; 1: + resid[m,n]; 2: + LN(resid)[m,n] (same mu/rs/lnw/lnb)
// Tile 64x64, BK=16, 256 threads, 4x4 microtile per thread.
// LDS leading-dim padded to 68 (stride%32==4 -> <=2-way conflicts; keeps 16B align).
// ---------------------------------------------------------------------------
template <int LN_A, int RES_MODE>
__global__ __launch_bounds__(256) void gemm64(
    const float* __restrict__ A, const float* __restrict__ W,
    const float* __restrict__ bias,
    const float* __restrict__ mu, const float* __restrict__ rs,
    const float* __restrict__ lnw, const float* __restrict__ lnb,
    const float* __restrict__ resid, float* __restrict__ C,
    int Mtot, int N, int K) {
    __shared__ float As[16][68];
    __shared__ float Ws[16][68];
    int tx = threadIdx.x & 15, ty = threadIdx.x >> 4;
    int m0 = blockIdx.x * 64, n0 = blockIdx.y * 64;
    float acc[4][4] = {};
    for (int k0 = 0; k0 < K; k0 += 16) {
        for (int l = threadIdx.x; l < 1024; l += 256) {
            int midx = l >> 4, kidx = l & 15;
            float v = A[(size_t)(m0 + midx) * K + k0 + kidx];
            if (LN_A)
                v = (v - mu[m0 + midx]) * rs[m0 + midx] * lnw[k0 + kidx] + lnb[k0 + kidx];
            As[kidx][midx] = v;
        }
        for (int l = threadIdx.x; l < 1024; l += 256) {
            int nidx = l >> 4, kidx = l & 15;
            Ws[kidx][nidx] = W[(size_t)(n0 + nidx) * K + k0 + kidx];
        }
        __syncthreads();
        for (int kk = 0; kk < 16; kk++) {
            float4 av = *(const float4*)&As[kk][ty * 4];
            float4 wv = *(const float4*)&Ws[kk][tx * 4];
            float a4[4] = {av.x, av.y, av.z, av.w};
            float w4[4] = {wv.x, wv.y, wv.z, wv.w};
            #pragma unroll
            for (int i = 0; i < 4; i++)
                #pragma unroll
                for (int j = 0; j < 4; j++) acc[i][j] += a4[i] * w4[j];
        }
        __syncthreads();
    }
    #pragma unroll
    for (int i = 0; i < 4; i++) {
        int m = m0 + ty * 4 + i;
        float4 o;
        float* op = (float*)&o;
        #pragma unroll
        for (int j = 0; j < 4; j++) {
            int n = n0 + tx * 4 + j;
            float v = acc[i][j] + bias[n];
            if (RES_MODE == 1) v += resid[(size_t)m * N + n];
            if (RES_MODE == 2) {
                float rv = resid[(size_t)m * N + n];
                v += (rv - mu[m]) * rs[m] * lnw[n] + lnb[n];
            }
            op[j] = v;
        }
        *(float4*)&C[(size_t)m * N + n0 + tx * 4] = o;
    }
}

// ---------------------------------------------------------------------------
// Attention: one block per (b, tile of TQ=8 q rows). Loops all 8 heads so
// attn_weights (mean over heads) accumulates in registers -> no atomics.
// Flash-style: full score row (1024) per q in LDS, never materialized globally.
// ---------------------------------------------------------------------------
__global__ __launch_bounds__(256) void attn_kernel(
    const float* __restrict__ q, const float* __restrict__ k,
    const float* __restrict__ v, float* __restrict__ ctx,
    float* __restrict__ aw) {
    __shared__ float s_p[TQ][1024];    // scores -> probabilities (32 KB)
    __shared__ float s_q[TQ][64];      // q tile for one head (2 KB)
    __shared__ float s_kv[64][68];     // staged K or V tile (17 KB, padded)

    int t = threadIdx.x;
    int bq = blockIdx.x;               // 0..1023
    int b  = bq >> 7;                  // 128 tiles per batch
    int q0 = (bq & 127) * TQ;
    const size_t baseB = (size_t)b * S * E;
    const float scale = 0.125f;        // 1/sqrt(64)

    float aw_reg[32];
    #pragma unroll
    for (int i = 0; i < 32; i++) aw_reg[i] = 0.f;

    int j  = t & 63;                   // score column within k-tile / ctx d index
    int qp = t >> 6;                   // 0..3 -> q-row pair

    for (int h = 0; h < H; h++) {
        // stage q tile for this head
        for (int l = t; l < TQ * 64; l += 256) {
            int qi = l >> 6, d = l & 63;
            s_q[qi][d] = q[baseB + (size_t)(q0 + qi) * E + h * 64 + d];
        }
        __syncthreads();

        // ---- scores: s_p[qi][kcol] = scale * q . k ----
        for (int kt = 0; kt < 16; kt++) {
            for (int l = t; l < 1024; l += 256) {
                int jj = l >> 4, d4 = l & 15;
                *(float4*)&s_kv[jj][d4 * 4] =
                    *(const float4*)&k[baseB + (size_t)(kt * 64 + jj) * E + h * 64 + d4 * 4];
            }
            __syncthreads();
            float acc0 = 0.f, acc1 = 0.f;
            #pragma unroll
            for (int d4 = 0; d4 < 16; d4++) {
                float4 kv4 = *(const float4*)&s_kv[j][d4 * 4];
                float4 qa  = *(const float4*)&s_q[qp * 2][d4 * 4];
                float4 qb  = *(const float4*)&s_q[qp * 2 + 1][d4 * 4];
                acc0 += qa.x * kv4.x + qa.y * kv4.y + qa.z * kv4.z + qa.w * kv4.w;
                acc1 += qb.x * kv4.x + qb.y * kv4.y + qb.z * kv4.z + qb.w * kv4.w;
            }
            s_p[qp * 2][kt * 64 + j]     = acc0 * scale;
            s_p[qp * 2 + 1][kt * 64 + j] = acc1 * scale;
            __syncthreads();
        }

        // ---- softmax: 32 threads per q row ----
        {
            int qi = t >> 5, lane = t & 31;
            float mloc = -1e30f;
            #pragma unroll
            for (int i = 0; i < 32; i++) mloc = fmaxf(mloc, s_p[qi][lane + 32 * i]);
            for (int o = 16; o > 0; o >>= 1) mloc = fmaxf(mloc, __shfl_xor(mloc, o, 32));
            float lsum = 0.f;
            #pragma unroll
            for (int i = 0; i < 32; i++) {
                float p = __expf(s_p[qi][lane + 32 * i] - mloc);
                s_p[qi][lane + 32 * i] = p;
                lsum += p;
            }
            for (int o = 16; o > 0; o >>= 1) lsum += __shfl_xor(lsum, o, 32);
            float linv = 1.0f / lsum;
            #pragma unroll
            for (int i = 0; i < 32; i++) {
                float p = s_p[qi][lane + 32 * i] * linv;
                s_p[qi][lane + 32 * i] = p;
                aw_reg[i] += p * (1.0f / H);
            }
        }
        __syncthreads();

        // ---- ctx: ctx[qi][d] = sum_k p * v ----
        float c0 = 0.f, c1 = 0.f;
        for (int kt = 0; kt < 16; kt++) {
            for (int l = t; l < 1024; l += 256) {
                int jj = l >> 4, d4 = l & 15;
                *(float4*)&s_kv[jj][d4 * 4] =
                    *(const float4*)&v[baseB + (size_t)(kt * 64 + jj) * E + h * 64 + d4 * 4];
            }
            __syncthreads();
            #pragma unroll 8
            for (int jj = 0; jj < 64; jj++) {
                float kvv = s_kv[jj][j];
                c0 += s_p[qp * 2][kt * 64 + jj] * kvv;
                c1 += s_p[qp * 2 + 1][kt * 64 + jj] * kvv;
            }
            __syncthreads();
        }
        ctx[baseB + (size_t)(q0 + qp * 2) * E + h * 64 + j]     = c0;
        ctx[baseB + (size_t)(q0 + qp * 2 + 1) * E + h * 64 + j] = c1;
        __syncthreads();
    }

    // ---- write attn_weights (mean over heads) ----
    {
        int qi = t >> 5, lane = t & 31;
        size_t awbase = ((size_t)b * S + q0 + qi) * S;
        #pragma unroll
        for (int i = 0; i < 32; i++) aw[awbase + lane + 32 * i] = aw_reg[i];
    }
}

// ---------------------------------------------------------------------------
extern "C" void kernel_launch(void* const* d_in, const int* in_sizes, int n_in,
                              void* d_out, int out_size, void* d_ws, size_t ws_size,
                              hipStream_t stream) {
    const float* Zab  = (const float*)d_in[0];
    const float* Za   = (const float*)d_in[1];
    const float* lnw  = (const float*)d_in[2];
    const float* lnb  = (const float*)d_in[3];
    const float* Wqkv = (const float*)d_in[4];
    const float* bqkv = (const float*)d_in[5];
    const float* Wo   = (const float*)d_in[6];
    const float* bo   = (const float*)d_in[7];
    const float* Wf   = (const float*)d_in[8];
    const float* bf   = (const float*)d_in[9];

    float* out_final = (float*)d_out;
    float* out_aw    = out_final + (size_t)B * S * E;

    char* ws = (char*)d_ws;
    float* qb = (float*)(ws);                         // 16 MB q   ; later t = x_n + ff
    float* kb = (float*)(ws + (16u << 20));           // 16 MB k   ; later x = attn_out + Zab
    float* vb = (float*)(ws + (32u << 20));           // 16 MB v
    float* cb = (float*)(ws + (48u << 20));           // 16 MB ctx
    float* muQ = (float*)(ws + (64u << 20));
    float* rsQ = muQ + M;
    float* muK = rsQ + M;
    float* rsK = muK + M;
    float* muX = rsK + M;
    float* rsX = muX + M;

    dim3 blk(256);
    dim3 gg(M / 64, E / 64);

    // 1. LN stats for both inputs
    ln_stats_kernel<<<M, blk, 0, stream>>>(Zab, muQ, rsQ);
    ln_stats_kernel<<<M, blk, 0, stream>>>(Za,  muK, rsK);

    // 2. q/k/v projections with fused LayerNorm on A
    gemm64<1, 0><<<gg, blk, 0, stream>>>(Zab, Wqkv,                   bqkv,         muQ, rsQ, lnw, lnb, nullptr, qb, M, E, E);
    gemm64<1, 0><<<gg, blk, 0, stream>>>(Za,  Wqkv + (size_t)E * E,   bqkv + E,     muK, rsK, lnw, lnb, nullptr, kb, M, E, E);
    gemm64<1, 0><<<gg, blk, 0, stream>>>(Za,  Wqkv + (size_t)2*E*E,   bqkv + 2*E,   muK, rsK, lnw, lnb, nullptr, vb, M, E, E);

    // 3. attention: ctx + attn_weights
    attn_kernel<<<B * (S / TQ), blk, 0, stream>>>(qb, kb, vb, cb, out_aw);

    // 4. out_proj + residual(Zab) -> x (reuse kb; k is dead)
    gemm64<0, 1><<<gg, blk, 0, stream>>>(cb, Wo, bo, nullptr, nullptr, nullptr, nullptr, Zab, kb, M, E, E);

    // 5. LN stats of x
    ln_stats_kernel<<<M, blk, 0, stream>>>(kb, muX, rsX);

    // 6. ff: t = LN(x) @ Wf^T + bf + LN(x)   (reuse qb; q is dead)
    gemm64<1, 2><<<gg, blk, 0, stream>>>(kb, Wf, bf, muX, rsX, lnw, lnb, kb, qb, M, E, E);

    // 7. final = LN(t)
    ln_full_kernel<<<M, blk, 0, stream>>>(qb, lnw, lnb, out_final);
}

// Round 2
// 773.983 us; speedup vs baseline: 2.3356x; 2.3356x over previous
//
#include <hip/hip_runtime.h>
#include <math.h>

#define EPS 1e-5f

constexpr int B = 8, S = 1024, E = 512, H = 8;
constexpr int M = B * S;          // 8192 rows

typedef __attribute__((ext_vector_type(8))) short short8;  // 8 bf16 (4 VGPRs)
typedef __attribute__((ext_vector_type(4))) float f32x4;

// fp32 -> bf16 bits, round-to-nearest-even
static __device__ __forceinline__ unsigned short f2bf(float f) {
    unsigned int x = __float_as_uint(f);
    x += 0x7FFFu + ((x >> 16) & 1u);
    return (unsigned short)(x >> 16);
}

// ---------------------------------------------------------------------------
// LN stats: per-row mean and rsqrt(var+eps). One block (256 thr) per row of E=512.
// ---------------------------------------------------------------------------
__global__ __launch_bounds__(256) void ln_stats_kernel(
    const float* __restrict__ x, float* __restrict__ mu, float* __restrict__ rs) {
    int row = blockIdx.x;
    const float* xr = x + (size_t)row * E;
    int t = threadIdx.x;
    float a = xr[t], c = xr[t + 256];
    __shared__ float red[256];
    red[t] = a + c; __syncthreads();
    for (int s2 = 128; s2 > 0; s2 >>= 1) { if (t < s2) red[t] += red[t + s2]; __syncthreads(); }
    float m = red[0] * (1.0f / E);
    __syncthreads();
    float d0 = a - m, d1 = c - m;
    red[t] = d0 * d0 + d1 * d1; __syncthreads();
    for (int s2 = 128; s2 > 0; s2 >>= 1) { if (t < s2) red[t] += red[t + s2]; __syncthreads(); }
    if (t == 0) { mu[row] = m; rs[row] = rsqrtf(red[0] * (1.0f / E) + EPS); }
}

// ---------------------------------------------------------------------------
// Full LN: out = (x - mu) * rsqrt(var+eps) * w + b   (final output stage)
// ---------------------------------------------------------------------------
__global__ __launch_bounds__(256) void ln_full_kernel(
    const float* __restrict__ x, const float* __restrict__ w,
    const float* __restrict__ bb, float* __restrict__ out) {
    int row = blockIdx.x;
    const float* xr = x + (size_t)row * E;
    int t = threadIdx.x;
    float a = xr[t], c = xr[t + 256];
    __shared__ float red[256];
    red[t] = a + c; __syncthreads();
    for (int s2 = 128; s2 > 0; s2 >>= 1) { if (t < s2) red[t] += red[t + s2]; __syncthreads(); }
    float m = red[0] * (1.0f / E);
    __syncthreads();
    float d0 = a - m, d1 = c - m;
    red[t] = d0 * d0 + d1 * d1; __syncthreads();
    for (int s2 = 128; s2 > 0; s2 >>= 1) { if (t < s2) red[t] += red[t + s2]; __syncthreads(); }
    float r = rsqrtf(red[0] * (1.0f / E) + EPS);
    float* orow = out + (size_t)row * E;
    orow[t]       = d0 * r * w[t]       + bb[t];
    orow[t + 256] = d1 * r * w[t + 256] + bb[t + 256];
}

// ---------------------------------------------------------------------------
// Tiled fp32 GEMM: C[M,N] = op(A)[M,K] @ W[N,K]^T + bias (+ epilogue)
//   LN_A: normalize A rows on the fly (fused LayerNorm)
//   RES_MODE 0: none; 1: + resid[m,n]; 2: + LN(resid)[m,n]
//   OUT_MODE 0: f32 [M,N]; 1: bf16 [M,N]; 2: bf16 transposed [B][N][S] (V^T)
// ---------------------------------------------------------------------------
template <int LN_A, int RES_MODE, int OUT_MODE>
__global__ __launch_bounds__(256) void gemm64(
    const float* __restrict__ A, const float* __restrict__ W,
    const float* __restrict__ bias,
    const float* __restrict__ mu, const float* __restrict__ rs,
    const float* __restrict__ lnw, const float* __restrict__ lnb,
    const float* __restrict__ resid, void* __restrict__ Cout,
    int Mtot, int N, int K) {
    __shared__ float As[16][68];
    __shared__ float Ws[16][68];
    int tx = threadIdx.x & 15, ty = threadIdx.x >> 4;
    int m0 = blockIdx.x * 64, n0 = blockIdx.y * 64;
    float acc[4][4] = {};
    for (int k0 = 0; k0 < K; k0 += 16) {
        for (int l = threadIdx.x; l < 1024; l += 256) {
            int midx = l >> 4, kidx = l & 15;
            float v = A[(size_t)(m0 + midx) * K + k0 + kidx];
            if (LN_A)
                v = (v - mu[m0 + midx]) * rs[m0 + midx] * lnw[k0 + kidx] + lnb[k0 + kidx];
            As[kidx][midx] = v;
        }
        for (int l = threadIdx.x; l < 1024; l += 256) {
            int nidx = l >> 4, kidx = l & 15;
            Ws[kidx][nidx] = W[(size_t)(n0 + nidx) * K + k0 + kidx];
        }
        __syncthreads();
        for (int kk = 0; kk < 16; kk++) {
            float4 av = *(const float4*)&As[kk][ty * 4];
            float4 wv = *(const float4*)&Ws[kk][tx * 4];
            float a4[4] = {av.x, av.y, av.z, av.w};
            float w4[4] = {wv.x, wv.y, wv.z, wv.w};
            #pragma unroll
            for (int i = 0; i < 4; i++)
                #pragma unroll
                for (int j = 0; j < 4; j++) acc[i][j] += a4[i] * w4[j];
        }
        __syncthreads();
    }
    float vv[4][4];
    #pragma unroll
    for (int i = 0; i < 4; i++) {
        int m = m0 + ty * 4 + i;
        #pragma unroll
        for (int j = 0; j < 4; j++) {
            int n = n0 + tx * 4 + j;
            float v = acc[i][j] + bias[n];
            if (RES_MODE == 1) v += resid[(size_t)m * N + n];
            if (RES_MODE == 2) {
                float rv = resid[(size_t)m * N + n];
                v += (rv - mu[m]) * rs[m] * lnw[n] + lnb[n];
            }
            vv[i][j] = v;
        }
    }
    if (OUT_MODE == 0) {
        #pragma unroll
        for (int i = 0; i < 4; i++) {
            int m = m0 + ty * 4 + i;
            float4 o = make_float4(vv[i][0], vv[i][1], vv[i][2], vv[i][3]);
            *(float4*)((float*)Cout + (size_t)m * N + n0 + tx * 4) = o;
        }
    } else if (OUT_MODE == 1) {
        #pragma unroll
        for (int i = 0; i < 4; i++) {
            int m = m0 + ty * 4 + i;
            ushort4 o;
            o.x = f2bf(vv[i][0]); o.y = f2bf(vv[i][1]);
            o.z = f2bf(vv[i][2]); o.w = f2bf(vv[i][3]);
            *(ushort4*)((unsigned short*)Cout + (size_t)m * N + n0 + tx * 4) = o;
        }
    } else {
        // transposed bf16: Cout[b][n][s], s = m % S
        int mm = m0 + ty * 4;
        int bb2 = mm >> 10, s0 = mm & 1023;
        #pragma unroll
        for (int j = 0; j < 4; j++) {
            int n = n0 + tx * 4 + j;
            ushort4 o;
            o.x = f2bf(vv[0][j]); o.y = f2bf(vv[1][j]);
            o.z = f2bf(vv[2][j]); o.w = f2bf(vv[3][j]);
            *(ushort4*)((unsigned short*)Cout + ((size_t)bb2 * N + n) * S + s0) = o;
        }
    }
}

// ---------------------------------------------------------------------------
// MFMA attention. Block = 4 waves = one (b, 16-q-row tile); loops 8 heads.
//   scores: A = Q frag (global, 16B/lane), B = K^T frag (global, 16B/lane),
//           wave w owns k-cols [w*256, w*256+256): 16 n-tiles x 2 k-steps.
//   softmax: 16-lane shuffle partials + cross-wave LDS exchange.
//   P: fp32 C-layout -> bf16 -> LDS (stride 1032: 2-way conflicts = free)
//      -> re-read in A-layout (m120 recipe).
//   PV: wave w owns d-tile [w*16, w*16+16), contracts full k=1024;
//       B = V^T frag read straight from global vt[B][E][S] (16B/lane).
//   attn_weights accumulate across heads in registers (C-layout, 64 f32/lane).
// ---------------------------------------------------------------------------
__global__ __launch_bounds__(256, 1) void attn_mfma_kernel(
    const unsigned short* __restrict__ q,   // [B][S][E] bf16
    const unsigned short* __restrict__ k,   // [B][S][E] bf16
    const unsigned short* __restrict__ vt,  // [B][E][S] bf16
    float* __restrict__ ctx,                // [B][S][E] f32
    float* __restrict__ aw) {               // [B][S][S] f32
    __shared__ unsigned short s_p[16][1032];
    __shared__ float s_red[2][4][16];

    const int t = threadIdx.x;
    const int wave = t >> 6, lane = t & 63;
    const int quad = lane >> 4, l16 = lane & 15;
    const int b = blockIdx.x >> 6;
    const int q0 = (blockIdx.x & 63) * 16;

    const size_t qrow = ((size_t)(b * S + q0 + l16)) * E;

    f32x4 awacc[16];
    #pragma unroll
    for (int i = 0; i < 16; i++) awacc[i] = (f32x4){0.f, 0.f, 0.f, 0.f};

    for (int h = 0; h < H; h++) {
        // ---- scores: S[16][1024] in C-layout across 4 waves ----
        short8 aq0 = *(const short8*)(q + qrow + h * 64 + quad * 8);
        short8 aq1 = *(const short8*)(q + qrow + h * 64 + 32 + quad * 8);
        f32x4 sacc[16];
        #pragma unroll
        for (int nt = 0; nt < 16; nt++) {
            const int kcol = wave * 256 + nt * 16 + l16;
            const unsigned short* kp = k + ((size_t)(b * S + kcol)) * E + h * 64 + quad * 8;
            short8 bk0 = *(const short8*)(kp);
            short8 bk1 = *(const short8*)(kp + 32);
            f32x4 c = (f32x4){0.f, 0.f, 0.f, 0.f};
            c = __builtin_amdgcn_mfma_f32_16x16x32_bf16(aq0, bk0, c, 0, 0, 0);
            c = __builtin_amdgcn_mfma_f32_16x16x32_bf16(aq1, bk1, c, 0, 0, 0);
            sacc[nt] = c * 0.125f;   // 1/sqrt(64)
        }

        // ---- softmax over full 1024 cols ----
        float gm[4], gs[4];
        #pragma unroll
        for (int r = 0; r < 4; r++) {
            float mv = sacc[0][r];
            #pragma unroll
            for (int nt = 1; nt < 16; nt++) mv = fmaxf(mv, sacc[nt][r]);
            #pragma unroll
            for (int o = 1; o < 16; o <<= 1) mv = fmaxf(mv, __shfl_xor(mv, o));
            gm[r] = mv;
        }
        if (l16 == 0) {
            #pragma unroll
            for (int r = 0; r < 4; r++) s_red[0][wave][quad * 4 + r] = gm[r];
        }
        __syncthreads();                                   // (A)
        #pragma unroll
        for (int r = 0; r < 4; r++) {
            int row = quad * 4 + r;
            gm[r] = fmaxf(fmaxf(s_red[0][0][row], s_red[0][1][row]),
                          fmaxf(s_red[0][2][row], s_red[0][3][row]));
        }
        float ls[4] = {0.f, 0.f, 0.f, 0.f};
        #pragma unroll
        for (int nt = 0; nt < 16; nt++)
            #pragma unroll
            for (int r = 0; r < 4; r++) {
                float p = __expf(sacc[nt][r] - gm[r]);
                sacc[nt][r] = p;
                ls[r] += p;
            }
        #pragma unroll
        for (int r = 0; r < 4; r++) {
            #pragma unroll
            for (int o = 1; o < 16; o <<= 1) ls[r] += __shfl_xor(ls[r], o);
        }
        if (l16 == 0) {
            #pragma unroll
            for (int r = 0; r < 4; r++) s_red[1][wave][quad * 4 + r] = ls[r];
        }
        __syncthreads();                                   // (B)
        #pragma unroll
        for (int r = 0; r < 4; r++) {
            int row = quad * 4 + r;
            gs[r] = 1.0f / (s_red[1][0][row] + s_red[1][1][row] +
                            s_red[1][2][row] + s_red[1][3][row]);
        }

        // ---- normalize, accumulate aw, write P (bf16) to LDS ----
        #pragma unroll
        for (int nt = 0; nt < 16; nt++) {
            #pragma unroll
            for (int r = 0; r < 4; r++) {
                float p = sacc[nt][r] * gs[r];
                awacc[nt][r] += p;
                s_p[quad * 4 + r][wave * 256 + nt * 16 + l16] = f2bf(p);
            }
        }
        __syncthreads();                                   // (C0) P visible

        // ---- PV: wave owns d-tile wave*16, contract full k=1024 ----
        f32x4 cacc = (f32x4){0.f, 0.f, 0.f, 0.f};
        const unsigned short* vrow =
            vt + ((size_t)(b * E + h * 64 + wave * 16 + l16)) * S;
        #pragma unroll 8
        for (int ks = 0; ks < 32; ks++) {
            short8 ap = *(const short8*)(&s_p[l16][ks * 32 + quad * 8]);
            short8 bv = *(const short8*)(vrow + ks * 32 + quad * 8);
            cacc = __builtin_amdgcn_mfma_f32_16x16x32_bf16(ap, bv, cacc, 0, 0, 0);
        }
        float* crow = ctx + ((size_t)(b * S + q0)) * E + h * 64 + wave * 16 + l16;
        #pragma unroll
        for (int r = 0; r < 4; r++)
            crow[(size_t)(quad * 4 + r) * E] = cacc[r];
        // next head's s_p writes are fenced by its own (A)+(B) barriers
    }

    // ---- attn_weights (mean over heads) ----
    #pragma unroll
    for (int nt = 0; nt < 16; nt++) {
        #pragma unroll
        for (int r = 0; r < 4; r++)
            aw[((size_t)(b * S + q0 + quad * 4 + r)) * S + wave * 256 + nt * 16 + l16] =
                awacc[nt][r] * (1.0f / H);
    }
}

// ---------------------------------------------------------------------------
extern "C" void kernel_launch(void* const* d_in, const int* in_sizes, int n_in,
                              void* d_out, int out_size, void* d_ws, size_t ws_size,
                              hipStream_t stream) {
    const float* Zab  = (const float*)d_in[0];
    const float* Za   = (const float*)d_in[1];
    const float* lnw  = (const float*)d_in[2];
    const float* lnb  = (const float*)d_in[3];
    const float* Wqkv = (const float*)d_in[4];
    const float* bqkv = (const float*)d_in[5];
    const float* Wo   = (const float*)d_in[6];
    const float* bo   = (const float*)d_in[7];
    const float* Wf   = (const float*)d_in[8];
    const float* bf   = (const float*)d_in[9];

    float* out_final = (float*)d_out;
    float* out_aw    = out_final + (size_t)B * S * E;

    char* ws = (char*)d_ws;
    unsigned short* qb  = (unsigned short*)(ws);               // 8 MB bf16 q
    unsigned short* kb  = (unsigned short*)(ws + (8u << 20));  // 8 MB bf16 k
    unsigned short* vtb = (unsigned short*)(ws + (16u << 20)); // 8 MB bf16 V^T
    float* cb = (float*)(ws + (24u << 20));                    // 16 MB ctx; later t
    float* xb = (float*)(ws + (40u << 20));                    // 16 MB x
    float* muQ = (float*)(ws + (56u << 20));
    float* rsQ = muQ + M;
    float* muK = rsQ + M;
    float* rsK = muK + M;
    float* muX = rsK + M;
    float* rsX = muX + M;

    dim3 blk(256);
    dim3 gg(M / 64, E / 64);

    // 1. LN stats for both inputs
    ln_stats_kernel<<<M, blk, 0, stream>>>(Zab, muQ, rsQ);
    ln_stats_kernel<<<M, blk, 0, stream>>>(Za,  muK, rsK);

    // 2. q/k/v projections with fused LayerNorm on A; bf16 outputs (V transposed)
    gemm64<1, 0, 1><<<gg, blk, 0, stream>>>(Zab, Wqkv,                 bqkv,       muQ, rsQ, lnw, lnb, nullptr, qb,  M, E, E);
    gemm64<1, 0, 1><<<gg, blk, 0, stream>>>(Za,  Wqkv + (size_t)E * E, bqkv + E,   muK, rsK, lnw, lnb, nullptr, kb,  M, E, E);
    gemm64<1, 0, 2><<<gg, blk, 0, stream>>>(Za,  Wqkv + (size_t)2*E*E, bqkv + 2*E, muK, rsK, lnw, lnb, nullptr, vtb, M, E, E);

    // 3. MFMA attention: ctx (f32) + attn_weights
    attn_mfma_kernel<<<B * (S / 16), blk, 0, stream>>>(qb, kb, vtb, cb, out_aw);

    // 4. out_proj + residual(Zab) -> x
    gemm64<0, 1, 0><<<gg, blk, 0, stream>>>(cb, Wo, bo, nullptr, nullptr, nullptr, nullptr, Zab, xb, M, E, E);

    // 5. LN stats of x
    ln_stats_kernel<<<M, blk, 0, stream>>>(xb, muX, rsX);

    // 6. ff: t = LN(x) @ Wf^T + bf + LN(x)   (into cb; ctx dead)
    gemm64<1, 2, 0><<<gg, blk, 0, stream>>>(xb, Wf, bf, muX, rsX, lnw, lnb, xb, cb, M, E, E);

    // 7. final = LN(t)
    ln_full_kernel<<<M, blk, 0, stream>>>(cb, lnw, lnb, out_final);
}

// Round 3
// 341.930 us; speedup vs baseline: 5.2869x; 2.2636x over previous
//
#include <hip/hip_runtime.h>
#include <math.h>

#define EPS 1e-5f

constexpr int B = 8, S = 1024, E = 512, H = 8;
constexpr int M = B * S;          // 8192 rows

typedef __attribute__((ext_vector_type(8))) short short8;  // 8 bf16 (4 VGPRs)
typedef __attribute__((ext_vector_type(4))) float f32x4;

// fp32 -> bf16 bits, round-to-nearest-even
static __device__ __forceinline__ unsigned short f2bf(float f) {
    unsigned int x = __float_as_uint(f);
    x += 0x7FFFu + ((x >> 16) & 1u);
    return (unsigned short)(x >> 16);
}
static __device__ __forceinline__ float bf2f(unsigned short u) {
    return __uint_as_float(((unsigned int)u) << 16);
}

// async global->LDS, 16B per lane (global_load_lds_dwordx4)
typedef __attribute__((address_space(3))) unsigned int  lds_uint;
typedef __attribute__((address_space(1))) unsigned int  glb_uint;
static __device__ __forceinline__ void gload16(const unsigned short* g, unsigned short* l) {
    __builtin_amdgcn_global_load_lds((const glb_uint*)g, (lds_uint*)l, 16, 0, 0);
}

// ---------------------------------------------------------------------------
// LN -> bf16: one wave per row (E=512, 8 elems/lane), stats via 64-lane shuffles.
// ---------------------------------------------------------------------------
__global__ __launch_bounds__(256) void ln_bf16_kernel(
    const float* __restrict__ x, const float* __restrict__ w,
    const float* __restrict__ bb, unsigned short* __restrict__ out) {
    int row = blockIdx.x * 4 + (threadIdx.x >> 6);
    int lane = threadIdx.x & 63;
    const float* xr = x + (size_t)row * E + lane * 8;
    float4 v0 = *(const float4*)xr;
    float4 v1 = *(const float4*)(xr + 4);
    float vv[8] = {v0.x, v0.y, v0.z, v0.w, v1.x, v1.y, v1.z, v1.w};
    float s = 0.f;
    #pragma unroll
    for (int i = 0; i < 8; i++) s += vv[i];
    #pragma unroll
    for (int o = 1; o < 64; o <<= 1) s += __shfl_xor(s, o);
    float mu = s * (1.0f / E);
    float qs = 0.f;
    #pragma unroll
    for (int i = 0; i < 8; i++) { float d = vv[i] - mu; qs += d * d; }
    #pragma unroll
    for (int o = 1; o < 64; o <<= 1) qs += __shfl_xor(qs, o);
    float rs = rsqrtf(qs * (1.0f / E) + EPS);
    float4 w0 = *(const float4*)(w + lane * 8), w1 = *(const float4*)(w + lane * 8 + 4);
    float4 b0 = *(const float4*)(bb + lane * 8), b1 = *(const float4*)(bb + lane * 8 + 4);
    float ww[8] = {w0.x, w0.y, w0.z, w0.w, w1.x, w1.y, w1.z, w1.w};
    float bv[8] = {b0.x, b0.y, b0.z, b0.w, b1.x, b1.y, b1.z, b1.w};
    short8 o8;
    #pragma unroll
    for (int i = 0; i < 8; i++) o8[i] = (short)f2bf((vv[i] - mu) * rs * ww[i] + bv[i]);
    *(short8*)(out + (size_t)row * E + lane * 8) = o8;
}

// ---------------------------------------------------------------------------
// Full LN (fp32 out) for the final output — wave-per-row.
// ---------------------------------------------------------------------------
__global__ __launch_bounds__(256) void ln_full_kernel(
    const float* __restrict__ x, const float* __restrict__ w,
    const float* __restrict__ bb, float* __restrict__ out) {
    int row = blockIdx.x * 4 + (threadIdx.x >> 6);
    int lane = threadIdx.x & 63;
    const float* xr = x + (size_t)row * E + lane * 8;
    float4 v0 = *(const float4*)xr;
    float4 v1 = *(const float4*)(xr + 4);
    float vv[8] = {v0.x, v0.y, v0.z, v0.w, v1.x, v1.y, v1.z, v1.w};
    float s = 0.f;
    #pragma unroll
    for (int i = 0; i < 8; i++) s += vv[i];
    #pragma unroll
    for (int o = 1; o < 64; o <<= 1) s += __shfl_xor(s, o);
    float mu = s * (1.0f / E);
    float qs = 0.f;
    #pragma unroll
    for (int i = 0; i < 8; i++) { float d = vv[i] - mu; qs += d * d; }
    #pragma unroll
    for (int o = 1; o < 64; o <<= 1) qs += __shfl_xor(qs, o);
    float rs = rsqrtf(qs * (1.0f / E) + EPS);
    float4 w0 = *(const float4*)(w + lane * 8), w1 = *(const float4*)(w + lane * 8 + 4);
    float4 b0 = *(const float4*)(bb + lane * 8), b1 = *(const float4*)(bb + lane * 8 + 4);
    float* op = out + (size_t)row * E + lane * 8;
    float4 o0, o1;
    o0.x = (vv[0] - mu) * rs * w0.x + b0.x;
    o0.y = (vv[1] - mu) * rs * w0.y + b0.y;
    o0.z = (vv[2] - mu) * rs * w0.z + b0.z;
    o0.w = (vv[3] - mu) * rs * w0.w + b0.w;
    o1.x = (vv[4] - mu) * rs * w1.x + b1.x;
    o1.y = (vv[5] - mu) * rs * w1.y + b1.y;
    o1.z = (vv[6] - mu) * rs * w1.z + b1.z;
    o1.w = (vv[7] - mu) * rs * w1.w + b1.w;
    *(float4*)op = o0;
    *(float4*)(op + 4) = o1;
}

// ---------------------------------------------------------------------------
// Weight conversion f32 -> bf16 into one packed buffer:
// [0,3EE): Wqkv   [3EE,4EE): Wo   [4EE,5EE): Wf
// ---------------------------------------------------------------------------
__global__ __launch_bounds__(256) void w2bf_kernel(
    const float* __restrict__ wqkv, const float* __restrict__ wo,
    const float* __restrict__ wf, unsigned short* __restrict__ out) {
    int base = (blockIdx.x * 256 + threadIdx.x) * 4;
    float4 v;
    if (base < 3 * E * E)           v = *(const float4*)(wqkv + base);
    else if (base < 4 * E * E)      v = *(const float4*)(wo + (base - 3 * E * E));
    else                            v = *(const float4*)(wf + (base - 4 * E * E));
    ushort4 o;
    o.x = f2bf(v.x); o.y = f2bf(v.y); o.z = f2bf(v.z); o.w = f2bf(v.w);
    *(ushort4*)(out + base) = o;
}

// ---------------------------------------------------------------------------
// bf16 MFMA GEMM (m97 structure): C[M,Ntot] = A[M,512] @ W[Ntot,512]^T + bias
// 128x128 tile, BK=32, 4 waves (2x2), each wave 64x64 = 4x4 MFMA 16x16x32.
// Staging via global_load_lds width 16 (no LDS padding — required by the DMA).
//   OUT_MODE 0: bf16 [M,Ntot] -> C0
//   OUT_MODE 1: f32  = acc + bias + residf          -> C0   (out_proj + Zab)
//   OUT_MODE 2: f32  = acc + bias + bf16(residb)    -> C0   (ff + LN(x))
//   OUT_MODE 3: kv-split: col<512 -> bf16 K [M,512] in C0;
//               col>=512 -> bf16 V^T [B][512][1024] in C1 (ushort4 runs of s)
// ---------------------------------------------------------------------------
template <int OUT_MODE>
__global__ __launch_bounds__(256) void gemm_mfma(
    const unsigned short* __restrict__ A, const unsigned short* __restrict__ W,
    const float* __restrict__ bias,
    const float* __restrict__ residf, const unsigned short* __restrict__ residb,
    void* __restrict__ C0, void* __restrict__ C1, int Ntot) {
    __shared__ unsigned short As[128 * 32];
    __shared__ unsigned short Bs[128 * 32];
    const int t = threadIdx.x;
    const int wave = t >> 6, lane = t & 63;
    const int quad = lane >> 4, l16 = lane & 15;
    const int m0 = blockIdx.x * 128, n0 = blockIdx.y * 128;
    const int wm = (wave >> 1) * 64, wn = (wave & 1) * 64;

    const int srow = t >> 2;            // staging row (0..63)
    const int skof = (t & 3) * 8;       // staging k-offset (elements)

    f32x4 acc[4][4];
    #pragma unroll
    for (int i = 0; i < 4; i++)
        #pragma unroll
        for (int j = 0; j < 4; j++) acc[i][j] = (f32x4){0.f, 0.f, 0.f, 0.f};

    for (int k0 = 0; k0 < E; k0 += 32) {
        gload16(A + (size_t)(m0 + srow) * E + k0 + skof,        As + t * 8);
        gload16(A + (size_t)(m0 + 64 + srow) * E + k0 + skof,   As + 2048 + t * 8);
        gload16(W + (size_t)(n0 + srow) * E + k0 + skof,        Bs + t * 8);
        gload16(W + (size_t)(n0 + 64 + srow) * E + k0 + skof,   Bs + 2048 + t * 8);
        __syncthreads();
        short8 af[4], bfr[4];
        #pragma unroll
        for (int i = 0; i < 4; i++)
            af[i] = *(const short8*)&As[(wm + i * 16 + l16) * 32 + quad * 8];
        #pragma unroll
        for (int j = 0; j < 4; j++)
            bfr[j] = *(const short8*)&Bs[(wn + j * 16 + l16) * 32 + quad * 8];
        #pragma unroll
        for (int i = 0; i < 4; i++)
            #pragma unroll
            for (int j = 0; j < 4; j++)
                acc[i][j] = __builtin_amdgcn_mfma_f32_16x16x32_bf16(af[i], bfr[j], acc[i][j], 0, 0, 0);
        __syncthreads();
    }

    // epilogue: lane holds C[m = tile_m + quad*4 + r][n = tile_n + l16]
    #pragma unroll
    for (int i = 0; i < 4; i++) {
        const int mrow0 = m0 + wm + i * 16 + quad * 4;
        #pragma unroll
        for (int j = 0; j < 4; j++) {
            const int ncol = n0 + wn + j * 16 + l16;
            const float bval = bias[ncol];
            if (OUT_MODE == 0) {
                #pragma unroll
                for (int r = 0; r < 4; r++)
                    ((unsigned short*)C0)[(size_t)(mrow0 + r) * Ntot + ncol] =
                        f2bf(acc[i][j][r] + bval);
            } else if (OUT_MODE == 1) {
                #pragma unroll
                for (int r = 0; r < 4; r++) {
                    size_t idx = (size_t)(mrow0 + r) * Ntot + ncol;
                    ((float*)C0)[idx] = acc[i][j][r] + bval + residf[idx];
                }
            } else if (OUT_MODE == 2) {
                #pragma unroll
                for (int r = 0; r < 4; r++) {
                    size_t idx = (size_t)(mrow0 + r) * Ntot + ncol;
                    ((float*)C0)[idx] = acc[i][j][r] + bval + bf2f(residb[idx]);
                }
            } else {
                if (ncol < 512) {
                    #pragma unroll
                    for (int r = 0; r < 4; r++)
                        ((unsigned short*)C0)[(size_t)(mrow0 + r) * 512 + ncol] =
                            f2bf(acc[i][j][r] + bval);
                } else {
                    const int nv = ncol - 512;
                    const int b2 = mrow0 >> 10, s0v = mrow0 & 1023;
                    ushort4 o;
                    o.x = f2bf(acc[i][j][0] + bval);
                    o.y = f2bf(acc[i][j][1] + bval);
                    o.z = f2bf(acc[i][j][2] + bval);
                    o.w = f2bf(acc[i][j][3] + bval);
                    *(ushort4*)((unsigned short*)C1 + ((size_t)b2 * 512 + nv) * 1024 + s0v) = o;
                }
            }
        }
    }
}

// ---------------------------------------------------------------------------
// MFMA attention (unchanged from round 2 except ctx output is bf16).
// ---------------------------------------------------------------------------
__global__ __launch_bounds__(256, 1) void attn_mfma_kernel(
    const unsigned short* __restrict__ q,   // [B][S][E] bf16
    const unsigned short* __restrict__ k,   // [B][S][E] bf16
    const unsigned short* __restrict__ vt,  // [B][E][S] bf16
    unsigned short* __restrict__ ctx,       // [B][S][E] bf16
    float* __restrict__ aw) {               // [B][S][S] f32
    __shared__ unsigned short s_p[16][1032];
    __shared__ float s_red[2][4][16];

    const int t = threadIdx.x;
    const int wave = t >> 6, lane = t & 63;
    const int quad = lane >> 4, l16 = lane & 15;
    const int b = blockIdx.x >> 6;
    const int q0 = (blockIdx.x & 63) * 16;

    const size_t qrow = ((size_t)(b * S + q0 + l16)) * E;

    f32x4 awacc[16];
    #pragma unroll
    for (int i = 0; i < 16; i++) awacc[i] = (f32x4){0.f, 0.f, 0.f, 0.f};

    for (int h = 0; h < H; h++) {
        short8 aq0 = *(const short8*)(q + qrow + h * 64 + quad * 8);
        short8 aq1 = *(const short8*)(q + qrow + h * 64 + 32 + quad * 8);
        f32x4 sacc[16];
        #pragma unroll
        for (int nt = 0; nt < 16; nt++) {
            const int kcol = wave * 256 + nt * 16 + l16;
            const unsigned short* kp = k + ((size_t)(b * S + kcol)) * E + h * 64 + quad * 8;
            short8 bk0 = *(const short8*)(kp);
            short8 bk1 = *(const short8*)(kp + 32);
            f32x4 c = (f32x4){0.f, 0.f, 0.f, 0.f};
            c = __builtin_amdgcn_mfma_f32_16x16x32_bf16(aq0, bk0, c, 0, 0, 0);
            c = __builtin_amdgcn_mfma_f32_16x16x32_bf16(aq1, bk1, c, 0, 0, 0);
            sacc[nt] = c * 0.125f;
        }

        float gm[4], gs[4];
        #pragma unroll
        for (int r = 0; r < 4; r++) {
            float mv = sacc[0][r];
            #pragma unroll
            for (int nt = 1; nt < 16; nt++) mv = fmaxf(mv, sacc[nt][r]);
            #pragma unroll
            for (int o = 1; o < 16; o <<= 1) mv = fmaxf(mv, __shfl_xor(mv, o));
            gm[r] = mv;
        }
        if (l16 == 0) {
            #pragma unroll
            for (int r = 0; r < 4; r++) s_red[0][wave][quad * 4 + r] = gm[r];
        }
        __syncthreads();
        #pragma unroll
        for (int r = 0; r < 4; r++) {
            int row = quad * 4 + r;
            gm[r] = fmaxf(fmaxf(s_red[0][0][row], s_red[0][1][row]),
                          fmaxf(s_red[0][2][row], s_red[0][3][row]));
        }
        float ls[4] = {0.f, 0.f, 0.f, 0.f};
        #pragma unroll
        for (int nt = 0; nt < 16; nt++)
            #pragma unroll
            for (int r = 0; r < 4; r++) {
                float p = __expf(sacc[nt][r] - gm[r]);
                sacc[nt][r] = p;
                ls[r] += p;
            }
        #pragma unroll
        for (int r = 0; r < 4; r++) {
            #pragma unroll
            for (int o = 1; o < 16; o <<= 1) ls[r] += __shfl_xor(ls[r], o);
        }
        if (l16 == 0) {
            #pragma unroll
            for (int r = 0; r < 4; r++) s_red[1][wave][quad * 4 + r] = ls[r];
        }
        __syncthreads();
        #pragma unroll
        for (int r = 0; r < 4; r++) {
            int row = quad * 4 + r;
            gs[r] = 1.0f / (s_red[1][0][row] + s_red[1][1][row] +
                            s_red[1][2][row] + s_red[1][3][row]);
        }

        #pragma unroll
        for (int nt = 0; nt < 16; nt++) {
            #pragma unroll
            for (int r = 0; r < 4; r++) {
                float p = sacc[nt][r] * gs[r];
                awacc[nt][r] += p;
                s_p[quad * 4 + r][wave * 256 + nt * 16 + l16] = f2bf(p);
            }
        }
        __syncthreads();

        f32x4 cacc = (f32x4){0.f, 0.f, 0.f, 0.f};
        const unsigned short* vrow =
            vt + ((size_t)(b * E + h * 64 + wave * 16 + l16)) * S;
        #pragma unroll 8
        for (int ks = 0; ks < 32; ks++) {
            short8 ap = *(const short8*)(&s_p[l16][ks * 32 + quad * 8]);
            short8 bv = *(const short8*)(vrow + ks * 32 + quad * 8);
            cacc = __builtin_amdgcn_mfma_f32_16x16x32_bf16(ap, bv, cacc, 0, 0, 0);
        }
        unsigned short* crow = ctx + ((size_t)(b * S + q0)) * E + h * 64 + wave * 16 + l16;
        #pragma unroll
        for (int r = 0; r < 4; r++)
            crow[(size_t)(quad * 4 + r) * E] = f2bf(cacc[r]);
    }

    #pragma unroll
    for (int nt = 0; nt < 16; nt++) {
        #pragma unroll
        for (int r = 0; r < 4; r++)
            aw[((size_t)(b * S + q0 + quad * 4 + r)) * S + wave * 256 + nt * 16 + l16] =
                awacc[nt][r] * (1.0f / H);
    }
}

// ---------------------------------------------------------------------------
extern "C" void kernel_launch(void* const* d_in, const int* in_sizes, int n_in,
                              void* d_out, int out_size, void* d_ws, size_t ws_size,
                              hipStream_t stream) {
    const float* Zab  = (const float*)d_in[0];
    const float* Za   = (const float*)d_in[1];
    const float* lnw  = (const float*)d_in[2];
    const float* lnb  = (const float*)d_in[3];
    const float* Wqkv = (const float*)d_in[4];
    const float* bqkv = (const float*)d_in[5];
    const float* Wo   = (const float*)d_in[6];
    const float* bo   = (const float*)d_in[7];
    const float* Wf   = (const float*)d_in[8];
    const float* bf   = (const float*)d_in[9];

    float* out_final = (float*)d_out;
    float* out_aw    = out_final + (size_t)B * S * E;

    char* ws = (char*)d_ws;
    unsigned short* qb   = (unsigned short*)(ws);               // 8 MB  [0,8M)
    unsigned short* kb   = (unsigned short*)(ws + (8u << 20));  // 8 MB  [8,16M)
    unsigned short* vtb  = (unsigned short*)(ws + (16u << 20)); // 8 MB  [16,24M)
    unsigned short* ctxb = (unsigned short*)(ws + (24u << 20)); // 8 MB  [24,32M)
    unsigned short* aqb  = (unsigned short*)(ws + (32u << 20)); // 8 MB  [32,40M)  later xn_bf
    unsigned short* akvb = (unsigned short*)(ws + (40u << 20)); // 8 MB  [40,48M)
    unsigned short* wbf  = (unsigned short*)(ws + (48u << 20)); // 2.62 MB
    float* xb = (float*)(ws);                                   // 16 MB [0,16M)  (qb/kb dead)
    float* tb = (float*)(ws + (16u << 20));                     // 16 MB [16,32M) (vtb/ctxb dead)
    unsigned short* xnb = aqb;                                  // reuse

    dim3 blk(256);

    // 1. weights -> bf16 (packed: qkv | o | f)
    w2bf_kernel<<<(5 * E * E) / 1024, blk, 0, stream>>>(Wqkv, Wo, Wf, wbf);

    // 2. LN(Zab), LN(Za) -> bf16
    ln_bf16_kernel<<<M / 4, blk, 0, stream>>>(Zab, lnw, lnb, aqb);
    ln_bf16_kernel<<<M / 4, blk, 0, stream>>>(Za,  lnw, lnb, akvb);

    // 3. q = LN(Zab)@Wq^T + bq (bf16); kv = LN(Za)@[Wk;Wv]^T + b (K bf16, V^T bf16)
    gemm_mfma<0><<<dim3(M / 128, 4), blk, 0, stream>>>(aqb,  wbf,               bqkv,     nullptr, nullptr, qb, nullptr, 512);
    gemm_mfma<3><<<dim3(M / 128, 8), blk, 0, stream>>>(akvb, wbf + (size_t)E*E, bqkv + E, nullptr, nullptr, kb, vtb, 1024);

    // 4. attention -> ctx (bf16) + attn_weights
    attn_mfma_kernel<<<B * (S / 16), blk, 0, stream>>>(qb, kb, vtb, ctxb, out_aw);

    // 5. x = ctx@Wo^T + bo + Zab (f32)
    gemm_mfma<1><<<dim3(M / 128, 4), blk, 0, stream>>>(ctxb, wbf + (size_t)3*E*E, bo, Zab, nullptr, xb, nullptr, 512);

    // 6. xn = LN(x) -> bf16
    ln_bf16_kernel<<<M / 4, blk, 0, stream>>>(xb, lnw, lnb, xnb);

    // 7. t = xn@Wf^T + bf + xn (f32)
    gemm_mfma<2><<<dim3(M / 128, 4), blk, 0, stream>>>(xnb, wbf + (size_t)4*E*E, bf, nullptr, xnb, tb, nullptr, 512);

    // 8. final = LN(t)
    ln_full_kernel<<<M / 4, blk, 0, stream>>>(tb, lnw, lnb, out_final);
}